// Round 1
// baseline (521.712 us; speedup 1.0000x reference)
//
#include <hip/hip_runtime.h>
#include <hip/hip_bf16.h>
#include <cfloat>

#define N_NODES 50000
#define N_EDGES 800000
#define N_GRAPHS 50
#define FEAT 256
#define NEG_SLOPE 0.2f

typedef __attribute__((ext_vector_type(8))) short short8;
typedef __attribute__((ext_vector_type(4))) short shortx4;
typedef __attribute__((ext_vector_type(4))) float floatx4;

__device__ __forceinline__ float lrelu(float e) {
  return e > 0.f ? e : NEG_SLOPE * e;
}
__device__ __forceinline__ short f2bf(float f) {
  __hip_bfloat16 b = __float2bfloat16(f);
  return *(short*)&b;
}
__device__ __forceinline__ float bf2f(short s) {
  unsigned u = ((unsigned)(unsigned short)s) << 16;
  return __uint_as_float(u);
}

// ---- W prep (blocks 0..511) + dst histogram (blocks 512..) ----
// cnt pre-zeroed by memsetAsync (block order undefined).
__global__ __launch_bounds__(256) void wsplit_hist_kernel(
    const float* __restrict__ W1, const float* __restrict__ W2,
    short* __restrict__ H1, short* __restrict__ L1,
    short* __restrict__ H2, short* __restrict__ L2,
    const int* __restrict__ dst, int* __restrict__ cnt) {
  int b = blockIdx.x, t = threadIdx.x;
  if (b < 512) {
    const float* W = (b < 256) ? W1 : W2;
    short* Hp = (b < 256) ? H1 : H2;
    short* Lp = (b < 256) ? L1 : L2;
    int k = b & 255;
    float v = W[k * 256 + t];
    short h = f2bf(v);
    Hp[t * 256 + k] = h;
    Lp[t * 256 + k] = f2bf(v - bf2f(h));
  } else {
    int e = (b - 512) * 256 + t;
    if (e < N_EDGES) atomicAdd(&cnt[dst[e]], 1);
  }
}

// ---- block reduction of cnt -> bsum; block 0 also computes graph bounds ----
__global__ __launch_bounds__(256) void scan_partial_kernel(
    const int* __restrict__ cnt, int* __restrict__ bsum, int n,
    const int* __restrict__ batch, int* __restrict__ gstart) {
  __shared__ int buf[256];
  int t = threadIdx.x;
  int i = blockIdx.x * 256 + t;
  buf[t] = (i < n) ? cnt[i] : 0;
  __syncthreads();
  for (int off = 128; off >= 1; off >>= 1) {
    if (t < off) buf[t] += buf[t + off];
    __syncthreads();
  }
  if (t == 0) bsum[blockIdx.x] = buf[0];
  if (blockIdx.x == 0 && t <= N_GRAPHS) {
    int lo = 0, hi = N_NODES;
    while (lo < hi) {
      int mid = (lo + hi) >> 1;
      if (batch[mid] < t) lo = mid + 1; else hi = mid;
    }
    gstart[t] = lo;
  }
}

// ---- final scan: each block re-scans the block-sums in LDS ----
__global__ __launch_bounds__(256) void scan_final_kernel(
    const int* __restrict__ cnt, const int* __restrict__ bsum,
    int* __restrict__ offs, int* __restrict__ cursor, int n, int nb) {
  __shared__ int buf[256], sb[256];
  int t = threadIdx.x;
  int i = blockIdx.x * 256 + t;
  int v = (i < n) ? cnt[i] : 0;
  buf[t] = v;
  sb[t] = (t < nb) ? bsum[t] : 0;
  __syncthreads();
  for (int off = 1; off < 256; off <<= 1) {
    int y1 = (t >= off) ? buf[t - off] : 0;
    int y2 = (t >= off) ? sb[t - off] : 0;
    __syncthreads();
    buf[t] += y1;
    sb[t] += y2;
    __syncthreads();
  }
  int carry = (blockIdx.x > 0) ? sb[blockIdx.x - 1] : 0;
  int excl = buf[t] - v + carry;
  if (i < n) { offs[i] = excl; cursor[i] = excl; }
  if (blockIdx.x == 0 && t == 0) offs[N_NODES] = sb[nb - 1];
}

// ---- MFMA GEMM + fused attention dots; scatter blocks INTERLEAVED ----
// R9 structure: A-only LDS, double-buffered ([2][128][40] H + L = 40KB,
// same footprint as R8's 4 single buffers), ONE barrier per k-step,
// 2-deep global->reg prefetch pipeline. B fragments are loaded straight
// from global (weights = 256KB, permanently L2-hot) — removes half the
// LDS traffic/bank conflicts and the second barrier.
// SPLIT_IN=true: A comes pre-split as bf16 hi/lo (layer 2, produced by
// agg1 epilogue) — no convert in the inner loop.
template <int H, bool SCATTER, bool SPLIT_IN>
__global__ __launch_bounds__(256, 3) void gemm_mfma_kernel(
    const float* __restrict__ A, const short* __restrict__ AH,
    const short* __restrict__ AL,
    const short* __restrict__ WtH, const short* __restrict__ WtL,
    short* __restrict__ C16,
    const float* __restrict__ att_src, const float* __restrict__ att_dst,
    float* __restrict__ a_src, float* __restrict__ a_dst, int M,
    const int* __restrict__ esrc, const int* __restrict__ edst,
    int* __restrict__ cursor, int* __restrict__ ssrc) {
  int t = threadIdx.x;
  int yb = blockIdx.y;
  if constexpr (SCATTER) {
    if (yb & 1) {
      int part = (yb >> 1) * 2 + blockIdx.x;  // 0..781
      int base = part * 1024 + t;
#pragma unroll
      for (int j = 0; j < 4; j++) {
        int e = base + j * 256;
        if (e < N_EDGES) {
          int d = edst[e];
          int pos = atomicAdd(&cursor[d], 1);
          ssrc[pos] = esrc[e];
        }
      }
      return;
    }
    yb >>= 1;
  }
  __shared__ short AsH[2][128][40], AsL[2][128][40];
  int bm = yb * 128, bn = blockIdx.x * 128;
  int w = t >> 6, lane = t & 63;
  int wrow = (w & 1) * 64, wcol = (w >> 1) * 64;
  int m15 = lane & 15, q = lane >> 4;
  int sr = t >> 1, sk = (t & 1) * 16;
  floatx4 acc[4][4] = {};
  int arow = bm + sr;
  bool aval = arow < M;

  // prefetch registers (2-deep pipeline: tile k+2 in flight while tile
  // k+1 is staged to LDS and tile k is consumed by MFMA)
  float4 na0, na1, na2, na3;
  int4 nh0, nh1, nl0, nl1;
  auto issue_load = [&](int k0) {
    if constexpr (SPLIT_IN) {
      if (aval) {
        const short* Hp = AH + (size_t)arow * 256 + k0 + sk;
        const short* Lp = AL + (size_t)arow * 256 + k0 + sk;
        nh0 = *(const int4*)(Hp + 0);
        nh1 = *(const int4*)(Hp + 8);
        nl0 = *(const int4*)(Lp + 0);
        nl1 = *(const int4*)(Lp + 8);
      } else {
        nh0 = nh1 = nl0 = nl1 = make_int4(0, 0, 0, 0);
      }
    } else {
      if (aval) {
        const float* Ap = A + (size_t)arow * 256 + k0 + sk;
        na0 = *(const float4*)(Ap + 0);
        na1 = *(const float4*)(Ap + 4);
        na2 = *(const float4*)(Ap + 8);
        na3 = *(const float4*)(Ap + 12);
      } else {
        na0 = na1 = na2 = na3 = make_float4(0.f, 0.f, 0.f, 0.f);
      }
    }
  };
  auto stage = [&](int buf) {
    if constexpr (SPLIT_IN) {
      *(int4*)&AsH[buf][sr][sk + 0] = nh0;
      *(int4*)&AsH[buf][sr][sk + 8] = nh1;
      *(int4*)&AsL[buf][sr][sk + 0] = nl0;
      *(int4*)&AsL[buf][sr][sk + 8] = nl1;
    } else {
      float af[16];
      *(float4*)&af[0] = na0; *(float4*)&af[4] = na1;
      *(float4*)&af[8] = na2; *(float4*)&af[12] = na3;
      short th[16], tl[16];
#pragma unroll
      for (int j = 0; j < 16; j++) {
        short h = f2bf(af[j]);
        th[j] = h;
        tl[j] = f2bf(af[j] - bf2f(h));
      }
      *(int4*)&AsH[buf][sr][sk + 0] = *(int4*)&th[0];
      *(int4*)&AsH[buf][sr][sk + 8] = *(int4*)&th[8];
      *(int4*)&AsL[buf][sr][sk + 0] = *(int4*)&tl[0];
      *(int4*)&AsL[buf][sr][sk + 8] = *(int4*)&tl[8];
    }
  };

  issue_load(0);
  stage(0);
  issue_load(32);
  __syncthreads();
#pragma unroll 2
  for (int ks = 0; ks < 8; ks++) {
    int k0 = ks * 32;
    // buf[(ks+1)&1] was last read at iter ks-1, protected by that
    // iteration's end-of-loop barrier.
    if (ks + 1 < 8) stage((ks + 1) & 1);
    if (ks + 2 < 8) issue_load(k0 + 64);
    // B fragments straight from global: identical addresses the old LDS
    // path held, 16B/lane, all L2-hit (W hi+lo = 256KB total).
    short8 Bh[4], Bl[4];
#pragma unroll
    for (int c = 0; c < 4; c++) {
      size_t boff = (size_t)(bn + wcol + c * 16 + m15) * 256 + k0 + q * 8;
      Bh[c] = *(const short8*)(WtH + boff);
      Bl[c] = *(const short8*)(WtL + boff);
    }
#pragma unroll
    for (int r = 0; r < 4; r++) {
      short8 Ah = *(const short8*)&AsH[ks & 1][wrow + r * 16 + m15][q * 8];
      short8 Al = *(const short8*)&AsL[ks & 1][wrow + r * 16 + m15][q * 8];
#pragma unroll
      for (int c = 0; c < 4; c++) {
        acc[r][c] = __builtin_amdgcn_mfma_f32_16x16x32_bf16(Ah, Bh[c], acc[r][c], 0, 0, 0);
        acc[r][c] = __builtin_amdgcn_mfma_f32_16x16x32_bf16(Ah, Bl[c], acc[r][c], 0, 0, 0);
        acc[r][c] = __builtin_amdgcn_mfma_f32_16x16x32_bf16(Al, Bh[c], acc[r][c], 0, 0, 0);
      }
    }
    __syncthreads();
  }
  float asv[4], adv[4];
#pragma unroll
  for (int c = 0; c < 4; c++) {
    int col = bn + wcol + c * 16 + m15;
    asv[c] = att_src[col];
    adv[c] = att_dst[col];
  }
#pragma unroll
  for (int r = 0; r < 4; r++) {
#pragma unroll
    for (int p = 0; p < 4; p++) {
      int grow = bm + wrow + r * 16 + q * 4 + p;
      float s = acc[r][0][p] * asv[0] + acc[r][1][p] * asv[1] +
                acc[r][2][p] * asv[2] + acc[r][3][p] * asv[3];
      float d = acc[r][0][p] * adv[0] + acc[r][1][p] * adv[1] +
                acc[r][2][p] * adv[2] + acc[r][3][p] * adv[3];
#pragma unroll
      for (int o = 1; o < 16; o <<= 1) {
        s += __shfl_xor(s, o, 64);
        d += __shfl_xor(d, o, 64);
      }
      if (grow < M) {
        if (m15 == 0) {
          if constexpr (H == 4) {
            int head = (bn >> 6) + (wcol >> 6);
            a_src[grow * 4 + head] = s;
            a_dst[grow * 4 + head] = d;
          } else {
            atomicAdd(&a_src[grow], s);
            atomicAdd(&a_dst[grow], d);
          }
        }
#pragma unroll
        for (int c = 0; c < 4; c++) {
          int gcol = bn + wcol + c * 16 + m15;
          C16[(size_t)grow * 256 + gcol] = f2bf(acc[r][c][p]);
        }
      }
    }
  }
}

// ---- fully fused aggregate: in-register softmax (max-free) ----
// 256-thread blocks = 4 waves = 4 nodes.
// SPLIT_OUT=true (layer 1): write bf16 hi/lo split instead of fp32 —
// feeds gemm2's SPLIT_IN path with bit-identical values to what gemm2
// used to compute in-loop.
template <int CH, bool SPLIT_OUT>
__global__ __launch_bounds__(256) void agg_kernel(
    const short* __restrict__ h16, const float* __restrict__ a_src,
    const float* __restrict__ a_dst, const int* __restrict__ offs,
    const int* __restrict__ ssrc, const float* __restrict__ bias,
    float* __restrict__ out, short* __restrict__ outH,
    short* __restrict__ outL, float* __restrict__ z1,
    float* __restrict__ z2) {
  constexpr int H = 256 / CH;
  int n = blockIdx.x * 4 + (threadIdx.x >> 6);
  int lane = threadIdx.x & 63;
  if (n >= N_NODES) return;
  int head = (4 * lane) / CH;
  int start = offs[n], end = offs[n + 1];
  float adv = a_dst[n * H + head];
  if (z1 != nullptr && lane == 0) { z1[n] = 0.f; z2[n] = 0.f; }
  float l = 0.f;
  float acc0 = 0.f, acc1 = 0.f, acc2 = 0.f, acc3 = 0.f;
  int i = start;
  for (; i + 8 <= end; i += 8) {
    int s[8]; uint2 u[8]; float av[8];
#pragma unroll
    for (int j = 0; j < 8; j++) s[j] = ssrc[i + j];
#pragma unroll
    for (int j = 0; j < 8; j++)
      u[j] = *(const uint2*)(h16 + (size_t)s[j] * 256 + 4 * lane);
#pragma unroll
    for (int j = 0; j < 8; j++) av[j] = a_src[s[j] * H + head];
#pragma unroll
    for (int j = 0; j < 8; j++) {
      float p = __expf(lrelu(av[j] + adv));
      l += p;
      acc0 = fmaf(p, __uint_as_float(u[j].x << 16), acc0);
      acc1 = fmaf(p, __uint_as_float(u[j].x & 0xffff0000u), acc1);
      acc2 = fmaf(p, __uint_as_float(u[j].y << 16), acc2);
      acc3 = fmaf(p, __uint_as_float(u[j].y & 0xffff0000u), acc3);
    }
  }
  for (; i < end; i++) {
    int s = ssrc[i];
    uint2 u = *(const uint2*)(h16 + (size_t)s * 256 + 4 * lane);
    float p = __expf(lrelu(a_src[s * H + head] + adv));
    l += p;
    acc0 = fmaf(p, __uint_as_float(u.x << 16), acc0);
    acc1 = fmaf(p, __uint_as_float(u.x & 0xffff0000u), acc1);
    acc2 = fmaf(p, __uint_as_float(u.y << 16), acc2);
    acc3 = fmaf(p, __uint_as_float(u.y & 0xffff0000u), acc3);
  }
  float ilv = l > 0.f ? 1.f / l : 0.f;
  float4 bv = *(const float4*)(bias + 4 * lane);
  float4 o;
  o.x = fmaxf(fmaf(acc0, ilv, bv.x), 0.f);
  o.y = fmaxf(fmaf(acc1, ilv, bv.y), 0.f);
  o.z = fmaxf(fmaf(acc2, ilv, bv.z), 0.f);
  o.w = fmaxf(fmaf(acc3, ilv, bv.w), 0.f);
  if constexpr (SPLIT_OUT) {
    shortx4 hv, lv;
    hv.x = f2bf(o.x); lv.x = f2bf(o.x - bf2f(hv.x));
    hv.y = f2bf(o.y); lv.y = f2bf(o.y - bf2f(hv.y));
    hv.z = f2bf(o.z); lv.z = f2bf(o.z - bf2f(hv.z));
    hv.w = f2bf(o.w); lv.w = f2bf(o.w - bf2f(hv.w));
    *(shortx4*)(outH + (size_t)n * 256 + 4 * lane) = hv;
    *(shortx4*)(outL + (size_t)n * 256 + 4 * lane) = lv;
  } else {
    *(float4*)(out + (size_t)n * 256 + 4 * lane) = o;
  }
}

// ---- global mean pool + FC ----
#define POOL_PARTS 16
__global__ __launch_bounds__(256) void pool_partial_kernel(
    const float* __restrict__ h, const int* __restrict__ gstart,
    float* __restrict__ part) {
  int g = blockIdx.x, p = blockIdx.y, t = threadIdx.x;
  int s = gstart[g], e = gstart[g + 1];
  float acc = 0.f;
  for (int n = s + p; n < e; n += POOL_PARTS) acc += h[(size_t)n * 256 + t];
  part[((size_t)g * POOL_PARTS + p) * 256 + t] = acc;
}

__global__ __launch_bounds__(256) void poolfc_kernel(
    const float* __restrict__ part, const int* __restrict__ gstart,
    const float* __restrict__ W, const float* __restrict__ b,
    float* __restrict__ out) {
  int g = blockIdx.x, t = threadIdx.x;
  __shared__ float ps[256];
  float acc = 0.f;
#pragma unroll
  for (int p = 0; p < POOL_PARTS; p++)
    acc += part[((size_t)g * POOL_PARTS + p) * 256 + t];
  int cnt = gstart[g + 1] - gstart[g];
  ps[t] = acc / (float)(cnt > 0 ? cnt : 1);
  __syncthreads();
  float a2 = 0.f;
#pragma unroll 8
  for (int k = 0; k < 256; k++) a2 = fmaf(ps[k], W[k * 256 + t], a2);
  out[g * 256 + t] = fmaxf(a2 + b[t], 0.f);
}

extern "C" void kernel_launch(void* const* d_in, const int* in_sizes, int n_in,
                              void* d_out, int out_size, void* d_ws, size_t ws_size,
                              hipStream_t stream) {
  const float* x      = (const float*)d_in[0];
  const int*   ei     = (const int*)d_in[1];
  const int*   batch  = (const int*)d_in[2];
  const float* W1     = (const float*)d_in[3];
  const float* att_s1 = (const float*)d_in[4];
  const float* att_d1 = (const float*)d_in[5];
  const float* b1     = (const float*)d_in[6];
  const float* W2     = (const float*)d_in[7];
  const float* att_s2 = (const float*)d_in[8];
  const float* att_d2 = (const float*)d_in[9];
  const float* b2     = (const float*)d_in[10];
  const float* Wfc    = (const float*)d_in[11];
  const float* bfc    = (const float*)d_in[12];
  const int* src = ei;
  const int* dst = ei + N_EDGES;
  float* outp = (float*)d_out;

  char* ws = (char*)d_ws;
  size_t off = 0;
  auto alloc = [&](size_t bytes) -> char* {
    char* p = ws + off;
    off += (bytes + 255) & ~(size_t)255;
    return p;
  };
  float* x2_buf = (float*)alloc((size_t)N_NODES * FEAT * 4);
  short* h16    = (short*)alloc((size_t)N_NODES * FEAT * 2);
  float* as_buf = (float*)alloc((size_t)N_NODES * 4 * 4);
  float* ad_buf = (float*)alloc((size_t)N_NODES * 4 * 4);
  float* as2    = (float*)alloc((size_t)N_NODES * 4);
  float* ad2    = (float*)alloc((size_t)N_NODES * 4);
  float* part   = (float*)alloc((size_t)N_GRAPHS * POOL_PARTS * FEAT * 4);
  short* WtH1   = (short*)alloc((size_t)256 * 256 * 2);
  short* WtL1   = (short*)alloc((size_t)256 * 256 * 2);
  short* WtH2   = (short*)alloc((size_t)256 * 256 * 2);
  short* WtL2   = (short*)alloc((size_t)256 * 256 * 2);
  int* cnt    = (int*)alloc((size_t)N_NODES * 4);
  int* offs   = (int*)alloc((size_t)(N_NODES + 1) * 4);
  int* cursor = (int*)alloc((size_t)N_NODES * 4);
  int* ssrc   = (int*)alloc((size_t)N_EDGES * 4);
  int* bsum   = (int*)alloc((size_t)256 * 4);
  int* gstart = (int*)alloc((size_t)(N_GRAPHS + 1) * 4);

  // layer-2 input, pre-split bf16 hi/lo — ALIASES x2_buf (disjoint
  // lifetimes: x2H/x2L dead after gemm2 consumes them; agg2 then
  // overwrites x2_buf entirely before pool reads it).
  short* x2H = (short*)x2_buf;
  short* x2L = x2H + (size_t)N_NODES * FEAT;

  int eb = (N_EDGES + 255) / 256;   // 3125
  int nb = (N_NODES + 255) / 256;   // 196
  int gy = (N_NODES + 127) / 128;   // 391

  hipMemsetAsync(cnt, 0, (size_t)N_NODES * 4, stream);
  wsplit_hist_kernel<<<512 + eb, 256, 0, stream>>>(W1, W2, WtH1, WtL1, WtH2, WtL2,
                                                   dst, cnt);
  scan_partial_kernel<<<nb, 256, 0, stream>>>(cnt, bsum, N_NODES, batch, gstart);
  scan_final_kernel<<<nb, 256, 0, stream>>>(cnt, bsum, offs, cursor, N_NODES, nb);

  // layer 1: gemm + att epilogue, scatter blocks interleaved (odd y rows)
  dim3 g1(2, 2 * gy);
  gemm_mfma_kernel<4, true, false><<<g1, 256, 0, stream>>>(
      x, nullptr, nullptr, WtH1, WtL1, h16, att_s1, att_d1, as_buf, ad_buf,
      N_NODES, src, dst, cursor, ssrc);
  agg_kernel<64, true><<<(N_NODES + 3) / 4, 256, 0, stream>>>(
      h16, as_buf, ad_buf, offs, ssrc, b1, nullptr, x2H, x2L, as2, ad2);
  // layer 2: H=1 (as2/ad2 pre-zeroed by layer-1 agg), pre-split input
  dim3 g2(2, gy);
  gemm_mfma_kernel<1, false, true><<<g2, 256, 0, stream>>>(
      nullptr, x2H, x2L, WtH2, WtL2, h16, att_s2, att_d2, as2, ad2,
      N_NODES, nullptr, nullptr, nullptr, nullptr);
  agg_kernel<256, false><<<(N_NODES + 3) / 4, 256, 0, stream>>>(
      h16, as2, ad2, offs, ssrc, b2, x2_buf, nullptr, nullptr,
      nullptr, nullptr);
  pool_partial_kernel<<<dim3(N_GRAPHS, POOL_PARTS), 256, 0, stream>>>(x2_buf, gstart, part);
  poolfc_kernel<<<N_GRAPHS, 256, 0, stream>>>(part, gstart, Wfc, bfc, outp);
}

// Round 2
// 494.717 us; speedup vs baseline: 1.0546x; 1.0546x over previous
//
#include <hip/hip_runtime.h>
#include <hip/hip_bf16.h>
#include <cfloat>

#define N_NODES 50000
#define N_EDGES 800000
#define N_GRAPHS 50
#define FEAT 256
#define NEG_SLOPE 0.2f

typedef __attribute__((ext_vector_type(8))) short short8;
typedef __attribute__((ext_vector_type(4))) short shortx4;
typedef __attribute__((ext_vector_type(4))) float floatx4;

__device__ __forceinline__ float lrelu(float e) {
  return e > 0.f ? e : NEG_SLOPE * e;
}
__device__ __forceinline__ short f2bf(float f) {
  __hip_bfloat16 b = __float2bfloat16(f);
  return *(short*)&b;
}
__device__ __forceinline__ float bf2f(short s) {
  unsigned u = ((unsigned)(unsigned short)s) << 16;
  return __uint_as_float(u);
}

// ---- W prep (blocks 0..511) + dst histogram (blocks 512..) ----
// cnt pre-zeroed by memsetAsync (block order undefined).
__global__ __launch_bounds__(256) void wsplit_hist_kernel(
    const float* __restrict__ W1, const float* __restrict__ W2,
    short* __restrict__ H1, short* __restrict__ L1,
    short* __restrict__ H2, short* __restrict__ L2,
    const int* __restrict__ dst, int* __restrict__ cnt) {
  int b = blockIdx.x, t = threadIdx.x;
  if (b < 512) {
    const float* W = (b < 256) ? W1 : W2;
    short* Hp = (b < 256) ? H1 : H2;
    short* Lp = (b < 256) ? L1 : L2;
    int k = b & 255;
    float v = W[k * 256 + t];
    short h = f2bf(v);
    Hp[t * 256 + k] = h;
    Lp[t * 256 + k] = f2bf(v - bf2f(h));
  } else {
    int e = (b - 512) * 256 + t;
    if (e < N_EDGES) atomicAdd(&cnt[dst[e]], 1);
  }
}

// ---- block reduction of cnt -> bsum; block 0 also computes graph bounds ----
__global__ __launch_bounds__(256) void scan_partial_kernel(
    const int* __restrict__ cnt, int* __restrict__ bsum, int n,
    const int* __restrict__ batch, int* __restrict__ gstart) {
  __shared__ int buf[256];
  int t = threadIdx.x;
  int i = blockIdx.x * 256 + t;
  buf[t] = (i < n) ? cnt[i] : 0;
  __syncthreads();
  for (int off = 128; off >= 1; off >>= 1) {
    if (t < off) buf[t] += buf[t + off];
    __syncthreads();
  }
  if (t == 0) bsum[blockIdx.x] = buf[0];
  if (blockIdx.x == 0 && t <= N_GRAPHS) {
    int lo = 0, hi = N_NODES;
    while (lo < hi) {
      int mid = (lo + hi) >> 1;
      if (batch[mid] < t) lo = mid + 1; else hi = mid;
    }
    gstart[t] = lo;
  }
}

// ---- final scan: each block re-scans the block-sums in LDS ----
__global__ __launch_bounds__(256) void scan_final_kernel(
    const int* __restrict__ cnt, const int* __restrict__ bsum,
    int* __restrict__ offs, int* __restrict__ cursor, int n, int nb) {
  __shared__ int buf[256], sb[256];
  int t = threadIdx.x;
  int i = blockIdx.x * 256 + t;
  int v = (i < n) ? cnt[i] : 0;
  buf[t] = v;
  sb[t] = (t < nb) ? bsum[t] : 0;
  __syncthreads();
  for (int off = 1; off < 256; off <<= 1) {
    int y1 = (t >= off) ? buf[t - off] : 0;
    int y2 = (t >= off) ? sb[t - off] : 0;
    __syncthreads();
    buf[t] += y1;
    sb[t] += y2;
    __syncthreads();
  }
  int carry = (blockIdx.x > 0) ? sb[blockIdx.x - 1] : 0;
  int excl = buf[t] - v + carry;
  if (i < n) { offs[i] = excl; cursor[i] = excl; }
  if (blockIdx.x == 0 && t == 0) offs[N_NODES] = sb[nb - 1];
}

// ---- MFMA GEMM + fused attention dots; scatter blocks INTERLEAVED ----
// R10: B back in LDS (R9 lesson: streaming B from global thrashes L2 and
// amplifies the scatter's dirty-line write-backs, WRITE_SIZE 86->142MB).
// B double-buffered via global_load_lds (async, 0 VGPRs) with XOR-swizzled
// SOURCE + swizzled ds_read (both-sides rule) -> conflict-free B reads.
// A single LDS buffer, reg-prefetched 1 iteration ahead.
// Raw s_barrier: vmcnt(0) drain sits AFTER barrier-1 (prefetch had a full
// MFMA section to land); barrier-2 has NO vmem drain so the next tile's
// loads stay in flight (__syncthreads would drain them -> m97 stall).
template <int H, bool SCATTER, bool SPLIT_IN>
__global__ __launch_bounds__(256, 3) void gemm_mfma_kernel(
    const float* __restrict__ A, const short* __restrict__ AH,
    const short* __restrict__ AL,
    const short* __restrict__ WtH, const short* __restrict__ WtL,
    short* __restrict__ C16,
    const float* __restrict__ att_src, const float* __restrict__ att_dst,
    float* __restrict__ a_src, float* __restrict__ a_dst, int M,
    const int* __restrict__ esrc, const int* __restrict__ edst,
    int* __restrict__ cursor, int* __restrict__ ssrc) {
  int t = threadIdx.x;
  int yb = blockIdx.y;
  if constexpr (SCATTER) {
    if (yb & 1) {
      int part = (yb >> 1) * 2 + blockIdx.x;  // 0..781
      int base = part * 1024 + t;
#pragma unroll
      for (int j = 0; j < 4; j++) {
        int e = base + j * 256;
        if (e < N_EDGES) {
          int d = edst[e];
          int pos = atomicAdd(&cursor[d], 1);
          ssrc[pos] = esrc[e];
        }
      }
      return;
    }
    yb >>= 1;
  }
  __shared__ short AsH[128][40], AsL[128][40];          // 20 KB, padded
  __shared__ short BsH2[2][128][32], BsL2[2][128][32];  // 32 KB, swizzled
  int bm = yb * 128, bn = blockIdx.x * 128;
  int w = t >> 6, lane = t & 63;
  int wrow = (w & 1) * 64, wcol = (w >> 1) * 64;
  int m15 = lane & 15, q = lane >> 4;
  int sr = t >> 1, sk = (t & 1) * 16;
  floatx4 acc[4][4] = {};
  int arow = bm + sr;
  bool aval = arow < M;

  // A prefetch registers (1 tile ahead; 16 VGPRs)
  float4 na0, na1, na2, na3;
  int4 nh0, nh1, nl0, nl1;
  auto issue_load = [&](int k0) {
    if constexpr (SPLIT_IN) {
      if (aval) {
        const short* Hp = AH + (size_t)arow * 256 + k0 + sk;
        const short* Lp = AL + (size_t)arow * 256 + k0 + sk;
        nh0 = *(const int4*)(Hp + 0);
        nh1 = *(const int4*)(Hp + 8);
        nl0 = *(const int4*)(Lp + 0);
        nl1 = *(const int4*)(Lp + 8);
      } else {
        nh0 = nh1 = nl0 = nl1 = make_int4(0, 0, 0, 0);
      }
    } else {
      if (aval) {
        const float* Ap = A + (size_t)arow * 256 + k0 + sk;
        na0 = *(const float4*)(Ap + 0);
        na1 = *(const float4*)(Ap + 4);
        na2 = *(const float4*)(Ap + 8);
        na3 = *(const float4*)(Ap + 12);
      } else {
        na0 = na1 = na2 = na3 = make_float4(0.f, 0.f, 0.f, 0.f);
      }
    }
  };
  auto stage_a = [&]() {
    if constexpr (SPLIT_IN) {
      *(int4*)&AsH[sr][sk + 0] = nh0;
      *(int4*)&AsH[sr][sk + 8] = nh1;
      *(int4*)&AsL[sr][sk + 0] = nl0;
      *(int4*)&AsL[sr][sk + 8] = nl1;
    } else {
      float af[16];
      *(float4*)&af[0] = na0; *(float4*)&af[4] = na1;
      *(float4*)&af[8] = na2; *(float4*)&af[12] = na3;
      short th[16], tl[16];
#pragma unroll
      for (int j = 0; j < 16; j++) {
        short h = f2bf(af[j]);
        th[j] = h;
        tl[j] = f2bf(af[j] - bf2f(h));
      }
      *(int4*)&AsH[sr][sk + 0] = *(int4*)&th[0];
      *(int4*)&AsH[sr][sk + 8] = *(int4*)&th[8];
      *(int4*)&AsL[sr][sk + 0] = *(int4*)&tl[0];
      *(int4*)&AsL[sr][sk + 8] = *(int4*)&tl[8];
    }
  };
  // B tile (128 rows x 32 cols shorts) via global_load_lds: linear LDS
  // dest (rows of 64B = 4 slots of 16B), logical slot c stored at slot
  // c ^ (row&3) -> source address pre-swizzled, read swizzled.
  auto stage_b = [&](int k0, int buf) {
#pragma unroll
    for (int cb = 0; cb < 2; cb++) {
      int R = w * 32 + cb * 16;
      int r = R + (lane >> 2);
      int c = (lane & 3) ^ (r & 3);
      size_t goff = (size_t)(bn + r) * 256 + k0 + c * 8;
      __builtin_amdgcn_global_load_lds(
          (const __attribute__((address_space(1))) void*)(WtH + goff),
          (__attribute__((address_space(3))) void*)&BsH2[buf][R][0], 16, 0, 0);
      __builtin_amdgcn_global_load_lds(
          (const __attribute__((address_space(1))) void*)(WtL + goff),
          (__attribute__((address_space(3))) void*)&BsL2[buf][R][0], 16, 0, 0);
    }
  };

  // prologue: tile 0 staged + drained, tile 1 in flight across barrier
  stage_b(0, 0);
  issue_load(0);
  asm volatile("s_waitcnt vmcnt(0)" ::: "memory");
  stage_a();
  stage_b(32, 1);
  issue_load(32);
  asm volatile("s_waitcnt lgkmcnt(0)" ::: "memory");
  __builtin_amdgcn_s_barrier();

#pragma unroll 2
  for (int ks = 0; ks < 8; ks++) {
    int k0 = ks * 32;
    short8 Bh[4], Bl[4];
#pragma unroll
    for (int c = 0; c < 4; c++) {
      int brow = wcol + c * 16 + m15;
      int sw = (q ^ (brow & 3)) * 8;
      Bh[c] = *(const short8*)&BsH2[ks & 1][brow][sw];
      Bl[c] = *(const short8*)&BsL2[ks & 1][brow][sw];
    }
#pragma unroll
    for (int r = 0; r < 4; r++) {
      short8 Ah = *(const short8*)&AsH[wrow + r * 16 + m15][q * 8];
      short8 Al = *(const short8*)&AsL[wrow + r * 16 + m15][q * 8];
#pragma unroll
      for (int c = 0; c < 4; c++) {
        acc[r][c] = __builtin_amdgcn_mfma_f32_16x16x32_bf16(Ah, Bh[c], acc[r][c], 0, 0, 0);
        acc[r][c] = __builtin_amdgcn_mfma_f32_16x16x32_bf16(Ah, Bl[c], acc[r][c], 0, 0, 0);
        acc[r][c] = __builtin_amdgcn_mfma_f32_16x16x32_bf16(Al, Bh[c], acc[r][c], 0, 0, 0);
      }
    }
    if (ks < 7) {
      __builtin_amdgcn_s_barrier();                     // b1: tile-ks reads done
      asm volatile("s_waitcnt vmcnt(0)" ::: "memory");  // tile ks+1 (A regs + B lds) landed
      stage_a();                                        // A(ks+1) -> LDS
      if (ks < 6) {
        stage_b(k0 + 64, ks & 1);                       // B(ks+2) -> just-freed buf
        issue_load(k0 + 64);                            // A(ks+2) -> regs
      }
      asm volatile("s_waitcnt lgkmcnt(0)" ::: "memory");
      __builtin_amdgcn_s_barrier();                     // b2: NO vmem drain
    }
  }
  float asv[4], adv[4];
#pragma unroll
  for (int c = 0; c < 4; c++) {
    int col = bn + wcol + c * 16 + m15;
    asv[c] = att_src[col];
    adv[c] = att_dst[col];
  }
#pragma unroll
  for (int r = 0; r < 4; r++) {
#pragma unroll
    for (int p = 0; p < 4; p++) {
      int grow = bm + wrow + r * 16 + q * 4 + p;
      float s = acc[r][0][p] * asv[0] + acc[r][1][p] * asv[1] +
                acc[r][2][p] * asv[2] + acc[r][3][p] * asv[3];
      float d = acc[r][0][p] * adv[0] + acc[r][1][p] * adv[1] +
                acc[r][2][p] * adv[2] + acc[r][3][p] * adv[3];
#pragma unroll
      for (int o = 1; o < 16; o <<= 1) {
        s += __shfl_xor(s, o, 64);
        d += __shfl_xor(d, o, 64);
      }
      if (grow < M) {
        if (m15 == 0) {
          if constexpr (H == 4) {
            int head = (bn >> 6) + (wcol >> 6);
            a_src[grow * 4 + head] = s;
            a_dst[grow * 4 + head] = d;
          } else {
            atomicAdd(&a_src[grow], s);
            atomicAdd(&a_dst[grow], d);
          }
        }
#pragma unroll
        for (int c = 0; c < 4; c++) {
          int gcol = bn + wcol + c * 16 + m15;
          C16[(size_t)grow * 256 + gcol] = f2bf(acc[r][c][p]);
        }
      }
    }
  }
}

// ---- fully fused aggregate: in-register softmax (max-free) ----
// 256-thread blocks = 4 waves = 4 nodes.
// SPLIT_OUT=true (layer 1): write bf16 hi/lo split instead of fp32 —
// feeds gemm2's SPLIT_IN path with bit-identical values to what gemm2
// used to compute in-loop.
template <int CH, bool SPLIT_OUT>
__global__ __launch_bounds__(256) void agg_kernel(
    const short* __restrict__ h16, const float* __restrict__ a_src,
    const float* __restrict__ a_dst, const int* __restrict__ offs,
    const int* __restrict__ ssrc, const float* __restrict__ bias,
    float* __restrict__ out, short* __restrict__ outH,
    short* __restrict__ outL, float* __restrict__ z1,
    float* __restrict__ z2) {
  constexpr int H = 256 / CH;
  int n = blockIdx.x * 4 + (threadIdx.x >> 6);
  int lane = threadIdx.x & 63;
  if (n >= N_NODES) return;
  int head = (4 * lane) / CH;
  int start = offs[n], end = offs[n + 1];
  float adv = a_dst[n * H + head];
  if (z1 != nullptr && lane == 0) { z1[n] = 0.f; z2[n] = 0.f; }
  float l = 0.f;
  float acc0 = 0.f, acc1 = 0.f, acc2 = 0.f, acc3 = 0.f;
  int i = start;
  for (; i + 8 <= end; i += 8) {
    int s[8]; uint2 u[8]; float av[8];
#pragma unroll
    for (int j = 0; j < 8; j++) s[j] = ssrc[i + j];
#pragma unroll
    for (int j = 0; j < 8; j++)
      u[j] = *(const uint2*)(h16 + (size_t)s[j] * 256 + 4 * lane);
#pragma unroll
    for (int j = 0; j < 8; j++) av[j] = a_src[s[j] * H + head];
#pragma unroll
    for (int j = 0; j < 8; j++) {
      float p = __expf(lrelu(av[j] + adv));
      l += p;
      acc0 = fmaf(p, __uint_as_float(u[j].x << 16), acc0);
      acc1 = fmaf(p, __uint_as_float(u[j].x & 0xffff0000u), acc1);
      acc2 = fmaf(p, __uint_as_float(u[j].y << 16), acc2);
      acc3 = fmaf(p, __uint_as_float(u[j].y & 0xffff0000u), acc3);
    }
  }
  for (; i < end; i++) {
    int s = ssrc[i];
    uint2 u = *(const uint2*)(h16 + (size_t)s * 256 + 4 * lane);
    float p = __expf(lrelu(a_src[s * H + head] + adv));
    l += p;
    acc0 = fmaf(p, __uint_as_float(u.x << 16), acc0);
    acc1 = fmaf(p, __uint_as_float(u.x & 0xffff0000u), acc1);
    acc2 = fmaf(p, __uint_as_float(u.y << 16), acc2);
    acc3 = fmaf(p, __uint_as_float(u.y & 0xffff0000u), acc3);
  }
  float ilv = l > 0.f ? 1.f / l : 0.f;
  float4 bv = *(const float4*)(bias + 4 * lane);
  float4 o;
  o.x = fmaxf(fmaf(acc0, ilv, bv.x), 0.f);
  o.y = fmaxf(fmaf(acc1, ilv, bv.y), 0.f);
  o.z = fmaxf(fmaf(acc2, ilv, bv.z), 0.f);
  o.w = fmaxf(fmaf(acc3, ilv, bv.w), 0.f);
  if constexpr (SPLIT_OUT) {
    shortx4 hv, lv;
    hv.x = f2bf(o.x); lv.x = f2bf(o.x - bf2f(hv.x));
    hv.y = f2bf(o.y); lv.y = f2bf(o.y - bf2f(hv.y));
    hv.z = f2bf(o.z); lv.z = f2bf(o.z - bf2f(hv.z));
    hv.w = f2bf(o.w); lv.w = f2bf(o.w - bf2f(hv.w));
    *(shortx4*)(outH + (size_t)n * 256 + 4 * lane) = hv;
    *(shortx4*)(outL + (size_t)n * 256 + 4 * lane) = lv;
  } else {
    *(float4*)(out + (size_t)n * 256 + 4 * lane) = o;
  }
}

// ---- global mean pool + FC ----
#define POOL_PARTS 16
__global__ __launch_bounds__(256) void pool_partial_kernel(
    const float* __restrict__ h, const int* __restrict__ gstart,
    float* __restrict__ part) {
  int g = blockIdx.x, p = blockIdx.y, t = threadIdx.x;
  int s = gstart[g], e = gstart[g + 1];
  float acc = 0.f;
  for (int n = s + p; n < e; n += POOL_PARTS) acc += h[(size_t)n * 256 + t];
  part[((size_t)g * POOL_PARTS + p) * 256 + t] = acc;
}

__global__ __launch_bounds__(256) void poolfc_kernel(
    const float* __restrict__ part, const int* __restrict__ gstart,
    const float* __restrict__ W, const float* __restrict__ b,
    float* __restrict__ out) {
  int g = blockIdx.x, t = threadIdx.x;
  __shared__ float ps[256];
  float acc = 0.f;
#pragma unroll
  for (int p = 0; p < POOL_PARTS; p++)
    acc += part[((size_t)g * POOL_PARTS + p) * 256 + t];
  int cnt = gstart[g + 1] - gstart[g];
  ps[t] = acc / (float)(cnt > 0 ? cnt : 1);
  __syncthreads();
  float a2 = 0.f;
#pragma unroll 8
  for (int k = 0; k < 256; k++) a2 = fmaf(ps[k], W[k * 256 + t], a2);
  out[g * 256 + t] = fmaxf(a2 + b[t], 0.f);
}

extern "C" void kernel_launch(void* const* d_in, const int* in_sizes, int n_in,
                              void* d_out, int out_size, void* d_ws, size_t ws_size,
                              hipStream_t stream) {
  const float* x      = (const float*)d_in[0];
  const int*   ei     = (const int*)d_in[1];
  const int*   batch  = (const int*)d_in[2];
  const float* W1     = (const float*)d_in[3];
  const float* att_s1 = (const float*)d_in[4];
  const float* att_d1 = (const float*)d_in[5];
  const float* b1     = (const float*)d_in[6];
  const float* W2     = (const float*)d_in[7];
  const float* att_s2 = (const float*)d_in[8];
  const float* att_d2 = (const float*)d_in[9];
  const float* b2     = (const float*)d_in[10];
  const float* Wfc    = (const float*)d_in[11];
  const float* bfc    = (const float*)d_in[12];
  const int* src = ei;
  const int* dst = ei + N_EDGES;
  float* outp = (float*)d_out;

  char* ws = (char*)d_ws;
  size_t off = 0;
  auto alloc = [&](size_t bytes) -> char* {
    char* p = ws + off;
    off += (bytes + 255) & ~(size_t)255;
    return p;
  };
  float* x2_buf = (float*)alloc((size_t)N_NODES * FEAT * 4);
  short* h16    = (short*)alloc((size_t)N_NODES * FEAT * 2);
  float* as_buf = (float*)alloc((size_t)N_NODES * 4 * 4);
  float* ad_buf = (float*)alloc((size_t)N_NODES * 4 * 4);
  float* as2    = (float*)alloc((size_t)N_NODES * 4);
  float* ad2    = (float*)alloc((size_t)N_NODES * 4);
  float* part   = (float*)alloc((size_t)N_GRAPHS * POOL_PARTS * FEAT * 4);
  short* WtH1   = (short*)alloc((size_t)256 * 256 * 2);
  short* WtL1   = (short*)alloc((size_t)256 * 256 * 2);
  short* WtH2   = (short*)alloc((size_t)256 * 256 * 2);
  short* WtL2   = (short*)alloc((size_t)256 * 256 * 2);
  int* cnt    = (int*)alloc((size_t)N_NODES * 4);
  int* offs   = (int*)alloc((size_t)(N_NODES + 1) * 4);
  int* cursor = (int*)alloc((size_t)N_NODES * 4);
  int* ssrc   = (int*)alloc((size_t)N_EDGES * 4);
  int* bsum   = (int*)alloc((size_t)256 * 4);
  int* gstart = (int*)alloc((size_t)(N_GRAPHS + 1) * 4);

  // layer-2 input, pre-split bf16 hi/lo — ALIASES x2_buf (disjoint
  // lifetimes: x2H/x2L dead after gemm2 consumes them; agg2 then
  // overwrites x2_buf entirely before pool reads it).
  short* x2H = (short*)x2_buf;
  short* x2L = x2H + (size_t)N_NODES * FEAT;

  int eb = (N_EDGES + 255) / 256;   // 3125
  int nb = (N_NODES + 255) / 256;   // 196
  int gy = (N_NODES + 127) / 128;   // 391

  hipMemsetAsync(cnt, 0, (size_t)N_NODES * 4, stream);
  wsplit_hist_kernel<<<512 + eb, 256, 0, stream>>>(W1, W2, WtH1, WtL1, WtH2, WtL2,
                                                   dst, cnt);
  scan_partial_kernel<<<nb, 256, 0, stream>>>(cnt, bsum, N_NODES, batch, gstart);
  scan_final_kernel<<<nb, 256, 0, stream>>>(cnt, bsum, offs, cursor, N_NODES, nb);

  // layer 1: gemm + att epilogue, scatter blocks interleaved (odd y rows)
  dim3 g1(2, 2 * gy);
  gemm_mfma_kernel<4, true, false><<<g1, 256, 0, stream>>>(
      x, nullptr, nullptr, WtH1, WtL1, h16, att_s1, att_d1, as_buf, ad_buf,
      N_NODES, src, dst, cursor, ssrc);
  agg_kernel<64, true><<<(N_NODES + 3) / 4, 256, 0, stream>>>(
      h16, as_buf, ad_buf, offs, ssrc, b1, nullptr, x2H, x2L, as2, ad2);
  // layer 2: H=1 (as2/ad2 pre-zeroed by layer-1 agg), pre-split input
  dim3 g2(2, gy);
  gemm_mfma_kernel<1, false, true><<<g2, 256, 0, stream>>>(
      nullptr, x2H, x2L, WtH2, WtL2, h16, att_s2, att_d2, as2, ad2,
      N_NODES, nullptr, nullptr, nullptr, nullptr);
  agg_kernel<256, false><<<(N_NODES + 3) / 4, 256, 0, stream>>>(
      h16, as2, ad2, offs, ssrc, b2, x2_buf, nullptr, nullptr,
      nullptr, nullptr);
  pool_partial_kernel<<<dim3(N_GRAPHS, POOL_PARTS), 256, 0, stream>>>(x2_buf, gstart, part);
  poolfc_kernel<<<N_GRAPHS, 256, 0, stream>>>(part, gstart, Wfc, bfc, outp);
}

// Round 3
// 425.493 us; speedup vs baseline: 1.2261x; 1.1627x over previous
//
#include <hip/hip_runtime.h>
#include <hip/hip_bf16.h>
#include <cfloat>

#define N_NODES 50000
#define N_EDGES 800000
#define N_GRAPHS 50
#define FEAT 256
#define NEG_SLOPE 0.2f

typedef __attribute__((ext_vector_type(8))) short short8;
typedef __attribute__((ext_vector_type(4))) float floatx4;

__device__ __forceinline__ float lrelu(float e) {
  return e > 0.f ? e : NEG_SLOPE * e;
}
__device__ __forceinline__ short f2bf(float f) {
  __hip_bfloat16 b = __float2bfloat16(f);
  return *(short*)&b;
}
__device__ __forceinline__ float bf2f(short s) {
  unsigned u = ((unsigned)(unsigned short)s) << 16;
  return __uint_as_float(u);
}

// ---- W prep (blocks 0..511) + dst histogram (blocks 512..) ----
// cnt pre-zeroed by memsetAsync (block order undefined).
__global__ __launch_bounds__(256) void wsplit_hist_kernel(
    const float* __restrict__ W1, const float* __restrict__ W2,
    short* __restrict__ H1, short* __restrict__ L1,
    short* __restrict__ H2, short* __restrict__ L2,
    const int* __restrict__ dst, int* __restrict__ cnt) {
  int b = blockIdx.x, t = threadIdx.x;
  if (b < 512) {
    const float* W = (b < 256) ? W1 : W2;
    short* Hp = (b < 256) ? H1 : H2;
    short* Lp = (b < 256) ? L1 : L2;
    int k = b & 255;
    float v = W[k * 256 + t];
    short h = f2bf(v);
    Hp[t * 256 + k] = h;
    Lp[t * 256 + k] = f2bf(v - bf2f(h));
  } else {
    int e = (b - 512) * 256 + t;
    if (e < N_EDGES) atomicAdd(&cnt[dst[e]], 1);
  }
}

// ---- block reduction of cnt -> bsum; block 0 also computes graph bounds ----
__global__ __launch_bounds__(256) void scan_partial_kernel(
    const int* __restrict__ cnt, int* __restrict__ bsum, int n,
    const int* __restrict__ batch, int* __restrict__ gstart) {
  __shared__ int buf[256];
  int t = threadIdx.x;
  int i = blockIdx.x * 256 + t;
  buf[t] = (i < n) ? cnt[i] : 0;
  __syncthreads();
  for (int off = 128; off >= 1; off >>= 1) {
    if (t < off) buf[t] += buf[t + off];
    __syncthreads();
  }
  if (t == 0) bsum[blockIdx.x] = buf[0];
  if (blockIdx.x == 0 && t <= N_GRAPHS) {
    int lo = 0, hi = N_NODES;
    while (lo < hi) {
      int mid = (lo + hi) >> 1;
      if (batch[mid] < t) lo = mid + 1; else hi = mid;
    }
    gstart[t] = lo;
  }
}

// ---- final scan: each block re-scans the block-sums in LDS ----
__global__ __launch_bounds__(256) void scan_final_kernel(
    const int* __restrict__ cnt, const int* __restrict__ bsum,
    int* __restrict__ offs, int* __restrict__ cursor, int n, int nb) {
  __shared__ int buf[256], sb[256];
  int t = threadIdx.x;
  int i = blockIdx.x * 256 + t;
  int v = (i < n) ? cnt[i] : 0;
  buf[t] = v;
  sb[t] = (t < nb) ? bsum[t] : 0;
  __syncthreads();
  for (int off = 1; off < 256; off <<= 1) {
    int y1 = (t >= off) ? buf[t - off] : 0;
    int y2 = (t >= off) ? sb[t - off] : 0;
    __syncthreads();
    buf[t] += y1;
    sb[t] += y2;
    __syncthreads();
  }
  int carry = (blockIdx.x > 0) ? sb[blockIdx.x - 1] : 0;
  int excl = buf[t] - v + carry;
  if (i < n) { offs[i] = excl; cursor[i] = excl; }
  if (blockIdx.x == 0 && t == 0) offs[N_NODES] = sb[nb - 1];
}

// ---- MFMA GEMM + fused attention dots; scatter blocks INTERLEAVED ----
// R11 = exact R8 dataflow (verified best: 88us gemm1 / 433us total) with
// ONE delta: LDS buffers [128][40]-padded -> [128][32] XOR-swizzled.
// 40KB -> 32KB total LDS = 4 -> 5 resident blocks/CU (+25% latency
// hiding on a kernel where MfmaUtil/VALUBusy/HBM are all <21%).
// Swizzle: 16B chunk c (0..3) of row r stored at c ^ ((r>>1)&3); applied
// on BOTH ds-write and ds-read. Column-slice reads (16 lanes, fixed q)
// then land on 8 bank-groups x 2-way — 2-way is free (m136).
template <int H, bool SCATTER>
__global__ __launch_bounds__(256) void gemm_mfma_kernel(
    const float* __restrict__ A, const short* __restrict__ WtH,
    const short* __restrict__ WtL, short* __restrict__ C16,
    const float* __restrict__ att_src, const float* __restrict__ att_dst,
    float* __restrict__ a_src, float* __restrict__ a_dst, int M,
    const int* __restrict__ esrc, const int* __restrict__ edst,
    int* __restrict__ cursor, int* __restrict__ ssrc) {
  int t = threadIdx.x;
  int yb = blockIdx.y;
  if constexpr (SCATTER) {
    if (yb & 1) {
      int part = (yb >> 1) * 2 + blockIdx.x;  // 0..781
      int base = part * 1024 + t;
#pragma unroll
      for (int j = 0; j < 4; j++) {
        int e = base + j * 256;
        if (e < N_EDGES) {
          int d = edst[e];
          int pos = atomicAdd(&cursor[d], 1);
          ssrc[pos] = esrc[e];
        }
      }
      return;
    }
    yb >>= 1;
  }
  __shared__ short AsH[128][32], AsL[128][32], BsH[128][32], BsL[128][32];
  int bm = yb * 128, bn = blockIdx.x * 128;
  int w = t >> 6, lane = t & 63;
  int wrow = (w & 1) * 64, wcol = (w >> 1) * 64;
  int m15 = lane & 15, q = lane >> 4;
  int sr = t >> 1, sk = (t & 1) * 16;
  // swizzled chunk offsets for this thread's two 16B stage writes
  int g3 = (sr >> 1) & 3;
  int c0 = (((sk >> 3) + 0) ^ g3) * 8;
  int c1 = (((sk >> 3) + 1) ^ g3) * 8;
  floatx4 acc[4][4] = {};
  int arow = bm + sr;
  for (int k0 = 0; k0 < 256; k0 += 32) {
    float4 a0 = make_float4(0.f, 0.f, 0.f, 0.f), a1 = a0, a2 = a0, a3 = a0;
    if (arow < M) {
      const float* Ap = A + (size_t)arow * 256 + k0 + sk;
      a0 = *(const float4*)(Ap + 0);
      a1 = *(const float4*)(Ap + 4);
      a2 = *(const float4*)(Ap + 8);
      a3 = *(const float4*)(Ap + 12);
    }
    const short* BHp = WtH + (size_t)(bn + sr) * 256 + k0 + sk;
    const short* BLp = WtL + (size_t)(bn + sr) * 256 + k0 + sk;
    int4 bh0 = *(const int4*)(BHp);
    int4 bh1 = *(const int4*)(BHp + 8);
    int4 bl0 = *(const int4*)(BLp);
    int4 bl1 = *(const int4*)(BLp + 8);
    float af[16];
    *(float4*)&af[0] = a0; *(float4*)&af[4] = a1;
    *(float4*)&af[8] = a2; *(float4*)&af[12] = a3;
    short th[16], tl[16];
#pragma unroll
    for (int j = 0; j < 16; j++) {
      short h = f2bf(af[j]);
      th[j] = h;
      tl[j] = f2bf(af[j] - bf2f(h));
    }
    __syncthreads();
    *(int4*)&AsH[sr][c0] = *(int4*)&th[0];
    *(int4*)&AsH[sr][c1] = *(int4*)&th[8];
    *(int4*)&AsL[sr][c0] = *(int4*)&tl[0];
    *(int4*)&AsL[sr][c1] = *(int4*)&tl[8];
    *(int4*)&BsH[sr][c0] = bh0;
    *(int4*)&BsH[sr][c1] = bh1;
    *(int4*)&BsL[sr][c0] = bl0;
    *(int4*)&BsL[sr][c1] = bl1;
    __syncthreads();
    short8 Bh[4], Bl[4];
#pragma unroll
    for (int c = 0; c < 4; c++) {
      int Rb = wcol + c * 16 + m15;
      int sw = (q ^ ((Rb >> 1) & 3)) * 8;
      Bh[c] = *(const short8*)&BsH[Rb][sw];
      Bl[c] = *(const short8*)&BsL[Rb][sw];
    }
#pragma unroll
    for (int r = 0; r < 4; r++) {
      int Ra = wrow + r * 16 + m15;
      int sw = (q ^ ((Ra >> 1) & 3)) * 8;
      short8 Ah = *(const short8*)&AsH[Ra][sw];
      short8 Al = *(const short8*)&AsL[Ra][sw];
#pragma unroll
      for (int c = 0; c < 4; c++) {
        acc[r][c] = __builtin_amdgcn_mfma_f32_16x16x32_bf16(Ah, Bh[c], acc[r][c], 0, 0, 0);
        acc[r][c] = __builtin_amdgcn_mfma_f32_16x16x32_bf16(Ah, Bl[c], acc[r][c], 0, 0, 0);
        acc[r][c] = __builtin_amdgcn_mfma_f32_16x16x32_bf16(Al, Bh[c], acc[r][c], 0, 0, 0);
      }
    }
  }
  float asv[4], adv[4];
#pragma unroll
  for (int c = 0; c < 4; c++) {
    int col = bn + wcol + c * 16 + m15;
    asv[c] = att_src[col];
    adv[c] = att_dst[col];
  }
#pragma unroll
  for (int r = 0; r < 4; r++) {
#pragma unroll
    for (int p = 0; p < 4; p++) {
      int grow = bm + wrow + r * 16 + q * 4 + p;
      float s = acc[r][0][p] * asv[0] + acc[r][1][p] * asv[1] +
                acc[r][2][p] * asv[2] + acc[r][3][p] * asv[3];
      float d = acc[r][0][p] * adv[0] + acc[r][1][p] * adv[1] +
                acc[r][2][p] * adv[2] + acc[r][3][p] * adv[3];
#pragma unroll
      for (int o = 1; o < 16; o <<= 1) {
        s += __shfl_xor(s, o, 64);
        d += __shfl_xor(d, o, 64);
      }
      if (grow < M) {
        if (m15 == 0) {
          if constexpr (H == 4) {
            int head = (bn >> 6) + (wcol >> 6);
            a_src[grow * 4 + head] = s;
            a_dst[grow * 4 + head] = d;
          } else {
            atomicAdd(&a_src[grow], s);
            atomicAdd(&a_dst[grow], d);
          }
        }
#pragma unroll
        for (int c = 0; c < 4; c++) {
          int gcol = bn + wcol + c * 16 + m15;
          C16[(size_t)grow * 256 + gcol] = f2bf(acc[r][c][p]);
        }
      }
    }
  }
}

// ---- fully fused aggregate: in-register softmax (max-free) ----
// 256-thread blocks = 4 waves = 4 nodes (doubles resident waves vs 128).
template <int CH>
__global__ __launch_bounds__(256) void agg_kernel(
    const short* __restrict__ h16, const float* __restrict__ a_src,
    const float* __restrict__ a_dst, const int* __restrict__ offs,
    const int* __restrict__ ssrc, const float* __restrict__ bias,
    float* __restrict__ out, float* __restrict__ z1, float* __restrict__ z2) {
  constexpr int H = 256 / CH;
  int n = blockIdx.x * 4 + (threadIdx.x >> 6);
  int lane = threadIdx.x & 63;
  if (n >= N_NODES) return;
  int head = (4 * lane) / CH;
  int start = offs[n], end = offs[n + 1];
  float adv = a_dst[n * H + head];
  if (z1 != nullptr && lane == 0) { z1[n] = 0.f; z2[n] = 0.f; }
  float l = 0.f;
  float acc0 = 0.f, acc1 = 0.f, acc2 = 0.f, acc3 = 0.f;
  int i = start;
  for (; i + 8 <= end; i += 8) {
    int s[8]; uint2 u[8]; float av[8];
#pragma unroll
    for (int j = 0; j < 8; j++) s[j] = ssrc[i + j];
#pragma unroll
    for (int j = 0; j < 8; j++)
      u[j] = *(const uint2*)(h16 + (size_t)s[j] * 256 + 4 * lane);
#pragma unroll
    for (int j = 0; j < 8; j++) av[j] = a_src[s[j] * H + head];
#pragma unroll
    for (int j = 0; j < 8; j++) {
      float p = __expf(lrelu(av[j] + adv));
      l += p;
      acc0 = fmaf(p, __uint_as_float(u[j].x << 16), acc0);
      acc1 = fmaf(p, __uint_as_float(u[j].x & 0xffff0000u), acc1);
      acc2 = fmaf(p, __uint_as_float(u[j].y << 16), acc2);
      acc3 = fmaf(p, __uint_as_float(u[j].y & 0xffff0000u), acc3);
    }
  }
  for (; i < end; i++) {
    int s = ssrc[i];
    uint2 u = *(const uint2*)(h16 + (size_t)s * 256 + 4 * lane);
    float p = __expf(lrelu(a_src[s * H + head] + adv));
    l += p;
    acc0 = fmaf(p, __uint_as_float(u.x << 16), acc0);
    acc1 = fmaf(p, __uint_as_float(u.x & 0xffff0000u), acc1);
    acc2 = fmaf(p, __uint_as_float(u.y << 16), acc2);
    acc3 = fmaf(p, __uint_as_float(u.y & 0xffff0000u), acc3);
  }
  float ilv = l > 0.f ? 1.f / l : 0.f;
  float4 bv = *(const float4*)(bias + 4 * lane);
  float4 o;
  o.x = fmaxf(fmaf(acc0, ilv, bv.x), 0.f);
  o.y = fmaxf(fmaf(acc1, ilv, bv.y), 0.f);
  o.z = fmaxf(fmaf(acc2, ilv, bv.z), 0.f);
  o.w = fmaxf(fmaf(acc3, ilv, bv.w), 0.f);
  *(float4*)(out + (size_t)n * 256 + 4 * lane) = o;
}

// ---- global mean pool + FC ----
#define POOL_PARTS 16
__global__ __launch_bounds__(256) void pool_partial_kernel(
    const float* __restrict__ h, const int* __restrict__ gstart,
    float* __restrict__ part) {
  int g = blockIdx.x, p = blockIdx.y, t = threadIdx.x;
  int s = gstart[g], e = gstart[g + 1];
  float acc = 0.f;
  for (int n = s + p; n < e; n += POOL_PARTS) acc += h[(size_t)n * 256 + t];
  part[((size_t)g * POOL_PARTS + p) * 256 + t] = acc;
}

__global__ __launch_bounds__(256) void poolfc_kernel(
    const float* __restrict__ part, const int* __restrict__ gstart,
    const float* __restrict__ W, const float* __restrict__ b,
    float* __restrict__ out) {
  int g = blockIdx.x, t = threadIdx.x;
  __shared__ float ps[256];
  float acc = 0.f;
#pragma unroll
  for (int p = 0; p < POOL_PARTS; p++)
    acc += part[((size_t)g * POOL_PARTS + p) * 256 + t];
  int cnt = gstart[g + 1] - gstart[g];
  ps[t] = acc / (float)(cnt > 0 ? cnt : 1);
  __syncthreads();
  float a2 = 0.f;
#pragma unroll 8
  for (int k = 0; k < 256; k++) a2 = fmaf(ps[k], W[k * 256 + t], a2);
  out[g * 256 + t] = fmaxf(a2 + b[t], 0.f);
}

extern "C" void kernel_launch(void* const* d_in, const int* in_sizes, int n_in,
                              void* d_out, int out_size, void* d_ws, size_t ws_size,
                              hipStream_t stream) {
  const float* x      = (const float*)d_in[0];
  const int*   ei     = (const int*)d_in[1];
  const int*   batch  = (const int*)d_in[2];
  const float* W1     = (const float*)d_in[3];
  const float* att_s1 = (const float*)d_in[4];
  const float* att_d1 = (const float*)d_in[5];
  const float* b1     = (const float*)d_in[6];
  const float* W2     = (const float*)d_in[7];
  const float* att_s2 = (const float*)d_in[8];
  const float* att_d2 = (const float*)d_in[9];
  const float* b2     = (const float*)d_in[10];
  const float* Wfc    = (const float*)d_in[11];
  const float* bfc    = (const float*)d_in[12];
  const int* src = ei;
  const int* dst = ei + N_EDGES;
  float* outp = (float*)d_out;

  char* ws = (char*)d_ws;
  size_t off = 0;
  auto alloc = [&](size_t bytes) -> char* {
    char* p = ws + off;
    off += (bytes + 255) & ~(size_t)255;
    return p;
  };
  float* x2_buf = (float*)alloc((size_t)N_NODES * FEAT * 4);
  short* h16    = (short*)alloc((size_t)N_NODES * FEAT * 2);
  float* as_buf = (float*)alloc((size_t)N_NODES * 4 * 4);
  float* ad_buf = (float*)alloc((size_t)N_NODES * 4 * 4);
  float* as2    = (float*)alloc((size_t)N_NODES * 4);
  float* ad2    = (float*)alloc((size_t)N_NODES * 4);
  float* part   = (float*)alloc((size_t)N_GRAPHS * POOL_PARTS * FEAT * 4);
  short* WtH1   = (short*)alloc((size_t)256 * 256 * 2);
  short* WtL1   = (short*)alloc((size_t)256 * 256 * 2);
  short* WtH2   = (short*)alloc((size_t)256 * 256 * 2);
  short* WtL2   = (short*)alloc((size_t)256 * 256 * 2);
  int* cnt    = (int*)alloc((size_t)N_NODES * 4);
  int* offs   = (int*)alloc((size_t)(N_NODES + 1) * 4);
  int* cursor = (int*)alloc((size_t)N_NODES * 4);
  int* ssrc   = (int*)alloc((size_t)N_EDGES * 4);
  int* bsum   = (int*)alloc((size_t)256 * 4);
  int* gstart = (int*)alloc((size_t)(N_GRAPHS + 1) * 4);

  int eb = (N_EDGES + 255) / 256;   // 3125
  int nb = (N_NODES + 255) / 256;   // 196
  int gy = (N_NODES + 127) / 128;   // 391

  hipMemsetAsync(cnt, 0, (size_t)N_NODES * 4, stream);
  wsplit_hist_kernel<<<512 + eb, 256, 0, stream>>>(W1, W2, WtH1, WtL1, WtH2, WtL2,
                                                   dst, cnt);
  scan_partial_kernel<<<nb, 256, 0, stream>>>(cnt, bsum, N_NODES, batch, gstart);
  scan_final_kernel<<<nb, 256, 0, stream>>>(cnt, bsum, offs, cursor, N_NODES, nb);

  // layer 1: gemm + att epilogue, scatter blocks interleaved (odd y rows)
  dim3 g1(2, 2 * gy);
  gemm_mfma_kernel<4, true><<<g1, 256, 0, stream>>>(x, WtH1, WtL1, h16,
                                                    att_s1, att_d1, as_buf, ad_buf,
                                                    N_NODES, src, dst, cursor, ssrc);
  agg_kernel<64><<<(N_NODES + 3) / 4, 256, 0, stream>>>(h16, as_buf, ad_buf, offs,
                                                        ssrc, b1, x2_buf, as2, ad2);
  // layer 2: H=1 (as2/ad2 pre-zeroed by layer-1 agg)
  dim3 g2(2, gy);
  gemm_mfma_kernel<1, false><<<g2, 256, 0, stream>>>(x2_buf, WtH2, WtL2, h16,
                                                     att_s2, att_d2, as2, ad2,
                                                     N_NODES, nullptr, nullptr,
                                                     nullptr, nullptr);
  agg_kernel<256><<<(N_NODES + 3) / 4, 256, 0, stream>>>(h16, as2, ad2, offs,
                                                         ssrc, b2, x2_buf,
                                                         nullptr, nullptr);
  pool_partial_kernel<<<dim3(N_GRAPHS, POOL_PARTS), 256, 0, stream>>>(x2_buf, gstart, part);
  poolfc_kernel<<<N_GRAPHS, 256, 0, stream>>>(part, gstart, Wfc, bfc, outp);
}

// Round 4
// 405.617 us; speedup vs baseline: 1.2862x; 1.0490x over previous
//
#include <hip/hip_runtime.h>
#include <hip/hip_bf16.h>
#include <cfloat>

#define N_NODES 50000
#define N_EDGES 800000
#define N_GRAPHS 50
#define FEAT 256
#define NEG_SLOPE 0.2f

#define NBUCKET 391   // ceil(50000/128); bucket b = dst >> 7
#define BCAP 3072     // capacity per bucket (mean 2046, sd ~45 -> >20 sigma slack)
#define P1_EDGES 8192
#define P1_BLOCKS 98  // 98*8192 = 802816 >= 800000

typedef __attribute__((ext_vector_type(8))) short short8;
typedef __attribute__((ext_vector_type(4))) float floatx4;

__device__ __forceinline__ float lrelu(float e) {
  return e > 0.f ? e : NEG_SLOPE * e;
}
__device__ __forceinline__ short f2bf(float f) {
  __hip_bfloat16 b = __float2bfloat16(f);
  return *(short*)&b;
}
__device__ __forceinline__ float bf2f(short s) {
  unsigned u = ((unsigned)(unsigned short)s) << 16;
  return __uint_as_float(u);
}

// ---- W prep (blocks 0..511) + pass-1 edge binning (blocks 512..609) ----
// Pass 1: block-local LDS histogram over 391 dst-buckets, one global
// atomicAdd per (bucket,block) to reserve a run, then append packed
// (src<<7)|dst&127. Runs are single-XCD writes into L2-resident bucket
// fronts (25KB) -> write amplification ~1 (vs 16x for the old per-node
// counting-sort scatter). gbcnt pre-zeroed by memsetAsync.
__global__ __launch_bounds__(256) void wsplit_pass1_kernel(
    const float* __restrict__ W1, const float* __restrict__ W2,
    short* __restrict__ H1, short* __restrict__ L1,
    short* __restrict__ H2, short* __restrict__ L2,
    const int* __restrict__ src, const int* __restrict__ dst,
    int* __restrict__ gbcnt, int* __restrict__ bdata) {
  int b = blockIdx.x, t = threadIdx.x;
  if (b < 512) {
    const float* W = (b < 256) ? W1 : W2;
    short* Hp = (b < 256) ? H1 : H2;
    short* Lp = (b < 256) ? L1 : L2;
    int k = b & 255;
    float v = W[k * 256 + t];
    short h = f2bf(v);
    Hp[t * 256 + k] = h;
    Lp[t * 256 + k] = f2bf(v - bf2f(h));
    return;
  }
  __shared__ int bb[NBUCKET];
  int base = (b - 512) * P1_EDGES;
  for (int i = t; i < NBUCKET; i += 256) bb[i] = 0;
  __syncthreads();
#pragma unroll 4
  for (int j = 0; j < P1_EDGES / 256; j++) {
    int e = base + j * 256 + t;
    if (e < N_EDGES) atomicAdd(&bb[dst[e] >> 7], 1);
  }
  __syncthreads();
  for (int i = t; i < NBUCKET; i += 256) {
    int c = bb[i];
    bb[i] = (c > 0) ? atomicAdd(&gbcnt[i], c) : 0;
  }
  __syncthreads();
#pragma unroll 4
  for (int j = 0; j < P1_EDGES / 256; j++) {
    int e = base + j * 256 + t;
    if (e < N_EDGES) {
      int d = dst[e];
      int bk = d >> 7;
      int p = atomicAdd(&bb[bk], 1);
      if (p < BCAP) bdata[bk * BCAP + p] = (src[e] << 7) | (d & 127);
    }
  }
}

// ---- exclusive scan of 391 bucket counts + graph bounds ----
__global__ __launch_bounds__(256) void bucketscan_kernel(
    const int* __restrict__ gbcnt, int* __restrict__ gboffs,
    int* __restrict__ offs, const int* __restrict__ batch,
    int* __restrict__ gstart) {
  __shared__ int s[512];
  int t = threadIdx.x;
  s[t] = (t < NBUCKET) ? gbcnt[t] : 0;
  s[t + 256] = (t + 256 < NBUCKET) ? gbcnt[t + 256] : 0;
  __syncthreads();
  for (int off = 1; off < 512; off <<= 1) {
    int v0 = (t >= off) ? s[t - off] : 0;
    int v1 = (t + 256 >= off) ? s[t + 256 - off] : 0;
    __syncthreads();
    s[t] += v0;
    s[t + 256] += v1;
    __syncthreads();
  }
  if (t < NBUCKET) gboffs[t] = (t == 0) ? 0 : s[t - 1];
  if (t + 256 < NBUCKET) gboffs[t + 256] = s[t + 255];
  if (t == 0) {
    gboffs[NBUCKET] = s[NBUCKET - 1];
    offs[N_NODES] = s[NBUCKET - 1];
  }
  if (t <= N_GRAPHS) {
    int lo = 0, hi = N_NODES;
    while (lo < hi) {
      int mid = (lo + hi) >> 1;
      if (batch[mid] < t) lo = mid + 1; else hi = mid;
    }
    gstart[t] = lo;
  }
}

// ---- MFMA GEMM + fused attention dots; pass-2 blocks INTERLEAVED ----
// GEMM path = R11 verified-best (XOR-swizzled [128][32] LDS, 0 bank
// conflicts, 32KB). Odd blockIdx.y rows (x==0) run pass-2: per 128-node
// bucket, LDS hist -> scan -> writes offs, LDS-cursor sort -> staged ssrc
// segment flushed as ONE coalesced streaming write. No global atomics,
// no write amplification (old scatter: ~51MB of line ping-pong, the
// empirical dur ~= WRITE/1.05TB/s law says that WAS the dispatch cost).
template <int H, bool SCATTER>
__global__ __launch_bounds__(256) void gemm_mfma_kernel(
    const float* __restrict__ A, const short* __restrict__ WtH,
    const short* __restrict__ WtL, short* __restrict__ C16,
    const float* __restrict__ att_src, const float* __restrict__ att_dst,
    float* __restrict__ a_src, float* __restrict__ a_dst, int M,
    const int* __restrict__ bdata, const int* __restrict__ gbcnt,
    const int* __restrict__ gboffs, int* __restrict__ offs,
    int* __restrict__ ssrc) {
  __shared__ __align__(16) char smem[32768];
  auto AsH = (short(*)[32])(smem);
  auto AsL = (short(*)[32])(smem + 8192);
  auto BsH = (short(*)[32])(smem + 16384);
  auto BsL = (short(*)[32])(smem + 24576);
  int t = threadIdx.x;
  int yb = blockIdx.y;
  if constexpr (SCATTER) {
    if (yb & 1) {
      if (blockIdx.x != 0) return;
      int bkt = yb >> 1;  // 0..390
      int nbase = bkt * 128;
      int nn = N_NODES - nbase; if (nn > 128) nn = 128;
      int cb = gbcnt[bkt]; if (cb > BCAP) cb = BCAP;
      int gb = gboffs[bkt];
      int* hist = (int*)smem;        // [128]
      int* cur = hist + 128;         // [128]
      int* stage = cur + 128;        // [3072]
      if (t < 128) hist[t] = 0;
      __syncthreads();
      const int* bd = bdata + bkt * BCAP;
      for (int i = t; i < cb; i += 256) atomicAdd(&hist[bd[i] & 127], 1);
      __syncthreads();
      if (t < 128) cur[t] = hist[t];
      __syncthreads();
      for (int off = 1; off < 128; off <<= 1) {
        int v = (t >= off && t < 128) ? cur[t - off] : 0;
        __syncthreads();
        if (t < 128) cur[t] += v;
        __syncthreads();
      }
      if (t < 128) {
        int excl = cur[t] - hist[t];
        if (t < nn) offs[nbase + t] = gb + excl;
        cur[t] = excl;  // local cursor
      }
      __syncthreads();
      for (int i = t; i < cb; i += 256) {
        int w = bd[i];
        int p = atomicAdd(&cur[w & 127], 1);
        stage[p] = w >> 7;
      }
      __syncthreads();
      for (int i = t; i < cb; i += 256) ssrc[gb + i] = stage[i];
      return;
    }
    yb >>= 1;
  }
  int bm = yb * 128, bn = blockIdx.x * 128;
  int w = t >> 6, lane = t & 63;
  int wrow = (w & 1) * 64, wcol = (w >> 1) * 64;
  int m15 = lane & 15, q = lane >> 4;
  int sr = t >> 1, sk = (t & 1) * 16;
  // swizzled chunk offsets for this thread's two 16B stage writes
  int g3 = (sr >> 1) & 3;
  int c0 = (((sk >> 3) + 0) ^ g3) * 8;
  int c1 = (((sk >> 3) + 1) ^ g3) * 8;
  floatx4 acc[4][4] = {};
  int arow = bm + sr;
  for (int k0 = 0; k0 < 256; k0 += 32) {
    float4 a0 = make_float4(0.f, 0.f, 0.f, 0.f), a1 = a0, a2 = a0, a3 = a0;
    if (arow < M) {
      const float* Ap = A + (size_t)arow * 256 + k0 + sk;
      a0 = *(const float4*)(Ap + 0);
      a1 = *(const float4*)(Ap + 4);
      a2 = *(const float4*)(Ap + 8);
      a3 = *(const float4*)(Ap + 12);
    }
    const short* BHp = WtH + (size_t)(bn + sr) * 256 + k0 + sk;
    const short* BLp = WtL + (size_t)(bn + sr) * 256 + k0 + sk;
    int4 bh0 = *(const int4*)(BHp);
    int4 bh1 = *(const int4*)(BHp + 8);
    int4 bl0 = *(const int4*)(BLp);
    int4 bl1 = *(const int4*)(BLp + 8);
    float af[16];
    *(float4*)&af[0] = a0; *(float4*)&af[4] = a1;
    *(float4*)&af[8] = a2; *(float4*)&af[12] = a3;
    short th[16], tl[16];
#pragma unroll
    for (int j = 0; j < 16; j++) {
      short h = f2bf(af[j]);
      th[j] = h;
      tl[j] = f2bf(af[j] - bf2f(h));
    }
    __syncthreads();
    *(int4*)&AsH[sr][c0] = *(int4*)&th[0];
    *(int4*)&AsH[sr][c1] = *(int4*)&th[8];
    *(int4*)&AsL[sr][c0] = *(int4*)&tl[0];
    *(int4*)&AsL[sr][c1] = *(int4*)&tl[8];
    *(int4*)&BsH[sr][c0] = bh0;
    *(int4*)&BsH[sr][c1] = bh1;
    *(int4*)&BsL[sr][c0] = bl0;
    *(int4*)&BsL[sr][c1] = bl1;
    __syncthreads();
    short8 Bh[4], Bl[4];
#pragma unroll
    for (int c = 0; c < 4; c++) {
      int Rb = wcol + c * 16 + m15;
      int sw = (q ^ ((Rb >> 1) & 3)) * 8;
      Bh[c] = *(const short8*)&BsH[Rb][sw];
      Bl[c] = *(const short8*)&BsL[Rb][sw];
    }
#pragma unroll
    for (int r = 0; r < 4; r++) {
      int Ra = wrow + r * 16 + m15;
      int sw = (q ^ ((Ra >> 1) & 3)) * 8;
      short8 Ah = *(const short8*)&AsH[Ra][sw];
      short8 Al = *(const short8*)&AsL[Ra][sw];
#pragma unroll
      for (int c = 0; c < 4; c++) {
        acc[r][c] = __builtin_amdgcn_mfma_f32_16x16x32_bf16(Ah, Bh[c], acc[r][c], 0, 0, 0);
        acc[r][c] = __builtin_amdgcn_mfma_f32_16x16x32_bf16(Ah, Bl[c], acc[r][c], 0, 0, 0);
        acc[r][c] = __builtin_amdgcn_mfma_f32_16x16x32_bf16(Al, Bh[c], acc[r][c], 0, 0, 0);
      }
    }
  }
  float asv[4], adv[4];
#pragma unroll
  for (int c = 0; c < 4; c++) {
    int col = bn + wcol + c * 16 + m15;
    asv[c] = att_src[col];
    adv[c] = att_dst[col];
  }
#pragma unroll
  for (int r = 0; r < 4; r++) {
#pragma unroll
    for (int p = 0; p < 4; p++) {
      int grow = bm + wrow + r * 16 + q * 4 + p;
      float s = acc[r][0][p] * asv[0] + acc[r][1][p] * asv[1] +
                acc[r][2][p] * asv[2] + acc[r][3][p] * asv[3];
      float d = acc[r][0][p] * adv[0] + acc[r][1][p] * adv[1] +
                acc[r][2][p] * adv[2] + acc[r][3][p] * adv[3];
#pragma unroll
      for (int o = 1; o < 16; o <<= 1) {
        s += __shfl_xor(s, o, 64);
        d += __shfl_xor(d, o, 64);
      }
      if (grow < M) {
        if (m15 == 0) {
          if constexpr (H == 4) {
            int head = (bn >> 6) + (wcol >> 6);
            a_src[grow * 4 + head] = s;
            a_dst[grow * 4 + head] = d;
          } else {
            atomicAdd(&a_src[grow], s);
            atomicAdd(&a_dst[grow], d);
          }
        }
#pragma unroll
        for (int c = 0; c < 4; c++) {
          int gcol = bn + wcol + c * 16 + m15;
          C16[(size_t)grow * 256 + gcol] = f2bf(acc[r][c][p]);
        }
      }
    }
  }
}

// ---- fully fused aggregate: in-register softmax (max-free) ----
// 256-thread blocks = 4 waves = 4 nodes.
template <int CH>
__global__ __launch_bounds__(256) void agg_kernel(
    const short* __restrict__ h16, const float* __restrict__ a_src,
    const float* __restrict__ a_dst, const int* __restrict__ offs,
    const int* __restrict__ ssrc, const float* __restrict__ bias,
    float* __restrict__ out, float* __restrict__ z1, float* __restrict__ z2) {
  constexpr int H = 256 / CH;
  int n = blockIdx.x * 4 + (threadIdx.x >> 6);
  int lane = threadIdx.x & 63;
  if (n >= N_NODES) return;
  int head = (4 * lane) / CH;
  int start = offs[n], end = offs[n + 1];
  float adv = a_dst[n * H + head];
  if (z1 != nullptr && lane == 0) { z1[n] = 0.f; z2[n] = 0.f; }
  float l = 0.f;
  float acc0 = 0.f, acc1 = 0.f, acc2 = 0.f, acc3 = 0.f;
  int i = start;
  for (; i + 8 <= end; i += 8) {
    int s[8]; uint2 u[8]; float av[8];
#pragma unroll
    for (int j = 0; j < 8; j++) s[j] = ssrc[i + j];
#pragma unroll
    for (int j = 0; j < 8; j++)
      u[j] = *(const uint2*)(h16 + (size_t)s[j] * 256 + 4 * lane);
#pragma unroll
    for (int j = 0; j < 8; j++) av[j] = a_src[s[j] * H + head];
#pragma unroll
    for (int j = 0; j < 8; j++) {
      float p = __expf(lrelu(av[j] + adv));
      l += p;
      acc0 = fmaf(p, __uint_as_float(u[j].x << 16), acc0);
      acc1 = fmaf(p, __uint_as_float(u[j].x & 0xffff0000u), acc1);
      acc2 = fmaf(p, __uint_as_float(u[j].y << 16), acc2);
      acc3 = fmaf(p, __uint_as_float(u[j].y & 0xffff0000u), acc3);
    }
  }
  for (; i < end; i++) {
    int s = ssrc[i];
    uint2 u = *(const uint2*)(h16 + (size_t)s * 256 + 4 * lane);
    float p = __expf(lrelu(a_src[s * H + head] + adv));
    l += p;
    acc0 = fmaf(p, __uint_as_float(u.x << 16), acc0);
    acc1 = fmaf(p, __uint_as_float(u.x & 0xffff0000u), acc1);
    acc2 = fmaf(p, __uint_as_float(u.y << 16), acc2);
    acc3 = fmaf(p, __uint_as_float(u.y & 0xffff0000u), acc3);
  }
  float ilv = l > 0.f ? 1.f / l : 0.f;
  float4 bv = *(const float4*)(bias + 4 * lane);
  float4 o;
  o.x = fmaxf(fmaf(acc0, ilv, bv.x), 0.f);
  o.y = fmaxf(fmaf(acc1, ilv, bv.y), 0.f);
  o.z = fmaxf(fmaf(acc2, ilv, bv.z), 0.f);
  o.w = fmaxf(fmaf(acc3, ilv, bv.w), 0.f);
  *(float4*)(out + (size_t)n * 256 + 4 * lane) = o;
}

// ---- global mean pool + FC ----
#define POOL_PARTS 16
__global__ __launch_bounds__(256) void pool_partial_kernel(
    const float* __restrict__ h, const int* __restrict__ gstart,
    float* __restrict__ part) {
  int g = blockIdx.x, p = blockIdx.y, t = threadIdx.x;
  int s = gstart[g], e = gstart[g + 1];
  float acc = 0.f;
  for (int n = s + p; n < e; n += POOL_PARTS) acc += h[(size_t)n * 256 + t];
  part[((size_t)g * POOL_PARTS + p) * 256 + t] = acc;
}

__global__ __launch_bounds__(256) void poolfc_kernel(
    const float* __restrict__ part, const int* __restrict__ gstart,
    const float* __restrict__ W, const float* __restrict__ b,
    float* __restrict__ out) {
  int g = blockIdx.x, t = threadIdx.x;
  __shared__ float ps[256];
  float acc = 0.f;
#pragma unroll
  for (int p = 0; p < POOL_PARTS; p++)
    acc += part[((size_t)g * POOL_PARTS + p) * 256 + t];
  int cnt = gstart[g + 1] - gstart[g];
  ps[t] = acc / (float)(cnt > 0 ? cnt : 1);
  __syncthreads();
  float a2 = 0.f;
#pragma unroll 8
  for (int k = 0; k < 256; k++) a2 = fmaf(ps[k], W[k * 256 + t], a2);
  out[g * 256 + t] = fmaxf(a2 + b[t], 0.f);
}

extern "C" void kernel_launch(void* const* d_in, const int* in_sizes, int n_in,
                              void* d_out, int out_size, void* d_ws, size_t ws_size,
                              hipStream_t stream) {
  const float* x      = (const float*)d_in[0];
  const int*   ei     = (const int*)d_in[1];
  const int*   batch  = (const int*)d_in[2];
  const float* W1     = (const float*)d_in[3];
  const float* att_s1 = (const float*)d_in[4];
  const float* att_d1 = (const float*)d_in[5];
  const float* b1     = (const float*)d_in[6];
  const float* W2     = (const float*)d_in[7];
  const float* att_s2 = (const float*)d_in[8];
  const float* att_d2 = (const float*)d_in[9];
  const float* b2     = (const float*)d_in[10];
  const float* Wfc    = (const float*)d_in[11];
  const float* bfc    = (const float*)d_in[12];
  const int* src = ei;
  const int* dst = ei + N_EDGES;
  float* outp = (float*)d_out;

  char* ws = (char*)d_ws;
  size_t off = 0;
  auto alloc = [&](size_t bytes) -> char* {
    char* p = ws + off;
    off += (bytes + 255) & ~(size_t)255;
    return p;
  };
  float* x2_buf = (float*)alloc((size_t)N_NODES * FEAT * 4);
  short* h16    = (short*)alloc((size_t)N_NODES * FEAT * 2);
  float* as_buf = (float*)alloc((size_t)N_NODES * 4 * 4);
  float* ad_buf = (float*)alloc((size_t)N_NODES * 4 * 4);
  float* as2    = (float*)alloc((size_t)N_NODES * 4);
  float* ad2    = (float*)alloc((size_t)N_NODES * 4);
  float* part   = (float*)alloc((size_t)N_GRAPHS * POOL_PARTS * FEAT * 4);
  short* WtH1   = (short*)alloc((size_t)256 * 256 * 2);
  short* WtL1   = (short*)alloc((size_t)256 * 256 * 2);
  short* WtH2   = (short*)alloc((size_t)256 * 256 * 2);
  short* WtL2   = (short*)alloc((size_t)256 * 256 * 2);
  int* offs   = (int*)alloc((size_t)(N_NODES + 1) * 4);
  int* ssrc   = (int*)alloc((size_t)N_EDGES * 4);
  int* bdata  = (int*)alloc((size_t)NBUCKET * BCAP * 4);
  int* gbcnt  = (int*)alloc((size_t)(NBUCKET + 1) * 4);
  int* gboffs = (int*)alloc((size_t)(NBUCKET + 1) * 4);
  int* gstart = (int*)alloc((size_t)(N_GRAPHS + 1) * 4);

  int gy = (N_NODES + 127) / 128;   // 391

  hipMemsetAsync(gbcnt, 0, (size_t)(NBUCKET + 1) * 4, stream);
  wsplit_pass1_kernel<<<512 + P1_BLOCKS, 256, 0, stream>>>(
      W1, W2, WtH1, WtL1, WtH2, WtL2, src, dst, gbcnt, bdata);
  bucketscan_kernel<<<1, 256, 0, stream>>>(gbcnt, gboffs, offs, batch, gstart);

  // layer 1: gemm + att epilogue, pass-2 bucket blocks interleaved (odd y)
  dim3 g1(2, 2 * gy);
  gemm_mfma_kernel<4, true><<<g1, 256, 0, stream>>>(
      x, WtH1, WtL1, h16, att_s1, att_d1, as_buf, ad_buf, N_NODES,
      bdata, gbcnt, gboffs, offs, ssrc);
  agg_kernel<64><<<(N_NODES + 3) / 4, 256, 0, stream>>>(h16, as_buf, ad_buf, offs,
                                                        ssrc, b1, x2_buf, as2, ad2);
  // layer 2: H=1 (as2/ad2 pre-zeroed by layer-1 agg)
  dim3 g2(2, gy);
  gemm_mfma_kernel<1, false><<<g2, 256, 0, stream>>>(
      x2_buf, WtH2, WtL2, h16, att_s2, att_d2, as2, ad2, N_NODES,
      nullptr, nullptr, nullptr, nullptr, nullptr);
  agg_kernel<256><<<(N_NODES + 3) / 4, 256, 0, stream>>>(h16, as2, ad2, offs,
                                                         ssrc, b2, x2_buf,
                                                         nullptr, nullptr);
  pool_partial_kernel<<<dim3(N_GRAPHS, POOL_PARTS), 256, 0, stream>>>(x2_buf, gstart, part);
  poolfc_kernel<<<N_GRAPHS, 256, 0, stream>>>(part, gstart, Wfc, bfc, outp);
}